// Round 6
// baseline (488.877 us; speedup 1.0000x reference)
//
#include <hip/hip_runtime.h>

// SoftCLDiceLoss fully fused, round 8 (retry — infra failure, kernel
// unchanged): 512-thread blocks for full occupancy.
// Evidence: per-SIMD VALU issue ~23%, LDS ~25-45%, conflicts ~80% hidden ->
// latency-bound at 16 waves/CU (LDS-capped 4 blocks x 4 waves). Keep LDS
// footprint (36.6 KB, 4 blocks/CU) but 8 waves/block -> 32 waves/CU, VGPR
// held <= 64 via __launch_bounds__(512,8). 32 strips: erode J=3 (96 slots
// >= 86-row max band), dilate J=2 (64 rows exact). Bank phases: dilate
// stride 2*52==8 mod 32 -> {0,8,16,24} balanced; erode stride 3*52==28 ->
// blk=(s&3)*4+((s>>2)&1)*16+(s>>3) gives in-wave Dphase=16. Complement
// skel update; vertical-first separable morphology; band
// [min(k+1,11), max(86-k,76)]; 2 syncs/iter.

#define TILE 64
#define HALO 12
#define RROWS 88
#define SD 52                    // row stride in dwords
#define IMG 1024
#define NBC 16
#define NITER 11
#define LEPS 1e-6f

typedef unsigned int u32;
typedef _Float16 hv2 __attribute__((ext_vector_type(2)));

struct __align__(16) U4 { u32 v[4]; };

__device__ __forceinline__ hv2 H2(u32 x) { union { u32 u; hv2 h; } c; c.u = x; return c.h; }
__device__ __forceinline__ u32 U2(hv2 x) { union { u32 u; hv2 h; } c; c.h = x; return c.u; }
__device__ __forceinline__ hv2 hmin2v(hv2 a, hv2 b) { return __builtin_elementwise_min(a, b); }
__device__ __forceinline__ hv2 hmax2v(hv2 a, hv2 b) { return __builtin_elementwise_max(a, b); }
__device__ __forceinline__ u32 dpp_prev16(u32 x) {   // lane i <- i-1 within 16-lane row, 0-fill
    return (u32)__builtin_amdgcn_update_dpp(0, (int)x, 0x101, 0xf, 0xf, true);
}
__device__ __forceinline__ u32 dpp_next16(u32 x) {   // lane i <- i+1 within 16-lane row, 0-fill
    return (u32)__builtin_amdgcn_update_dpp(0, (int)x, 0x111, 0xf, 0xf, true);
}
__device__ __forceinline__ u32 alignh(u32 hi, u32 lo) {   // (lo.hi16, hi.lo16) packed
    return (u32)((((unsigned long long)hi << 32) | lo) >> 16);
}
__device__ __forceinline__ float sigmoidf(float x) { return 1.0f / (1.0f + __expf(-x)); }

// 3-wide horizontal min/max over 8 packed halves; neighbors via DPP.
template<bool IS_MIN>
__device__ __forceinline__ void hpass(const u32 d[4], u32 o[4]) {
    u32 dm = dpp_prev16(d[3]);
    u32 dp = dpp_next16(d[0]);
    u32 a[5];
    a[0] = alignh(d[0], dm);
    a[1] = alignh(d[1], d[0]);
    a[2] = alignh(d[2], d[1]);
    a[3] = alignh(d[3], d[2]);
    a[4] = alignh(dp,   d[3]);
#pragma unroll
    for (int q = 0; q < 4; ++q) {
        if (IS_MIN) o[q] = U2(hmin2v(hmin2v(H2(a[q]), H2(d[q])), H2(a[q + 1])));
        else        o[q] = U2(hmax2v(hmax2v(H2(a[q]), H2(d[q])), H2(a[q + 1])));
    }
}

// One skel iteration: erode cur->oth (rows [lo,hi], 3 rows/strip, strip
// permuted for bank-phase spread), then dilate(oth)+delta(cur)+complement
// update (2 rows/strip). Vertical reduce before hpass in both phases.
__device__ __forceinline__ void iter_body(int k, u32* cur, u32* oth,
        int g16, int coldw, bool wact, int blk, int rs_d,
        bool edgeI, int rdLo, int rdHi, bool edgeL, bool edgeR,
        hv2 (&Cv)[2][4])
{
    // ---- erode 3x3 (min): cur -> oth, vertical-first, 3 rows/strip ----
    const int lo = min(k + 1, 11);           // needed band of erode output
    const int hi = max(86 - k, 76);
    const int rs_e = min(lo + 3 * blk, hi - 2);
    {
        const u32* p = cur + (rs_e - 1) * SD + coldw;
        u32* qo = oth + rs_e * SD + coldw;
        U4 r0, r1, r2;
        *(uint4*)r0.v = *(const uint4*)(p);
        *(uint4*)r1.v = *(const uint4*)(p + SD);
#pragma unroll
        for (int j = 0; j < 3; ++j) {
            *(uint4*)r2.v = *(const uint4*)(p + (j + 2) * SD);
            U4 vv, o;
#pragma unroll
            for (int q = 0; q < 4; ++q)
                vv.v[q] = U2(hmin2v(hmin2v(H2(r0.v[q]), H2(r1.v[q])), H2(r2.v[q])));
            hpass<true>(vv.v, o.v);
            if (wact) *(uint4*)(qo + j * SD) = *(const uint4*)o.v;
            r0 = r1; r1 = r2;
        }
    }
    __syncthreads();

    // ---- dilate 3x3 (max) on oth, vertical-first + delta vs cur + update ----
    {
        U4 w[4];
        if (edgeI) {
            const u32* p = oth + (rs_d - 1) * SD + coldw;
#pragma unroll
            for (int j = 0; j < 4; ++j)
                *(uint4*)w[j].v = *(const uint4*)(p + j * SD);
        } else {
#pragma unroll
            for (int j = 0; j < 4; ++j) {
                int rr = min(max(rs_d - 1 + j, rdLo), rdHi);
                *(uint4*)w[j].v = *(const uint4*)(oth + rr * SD + coldw);
            }
        }
        U4 V[2], m[2];
#pragma unroll
        for (int i = 0; i < 2; ++i) {
#pragma unroll
            for (int q = 0; q < 4; ++q)
                V[i].v[q] = U2(hmax2v(hmax2v(H2(w[i].v[q]), H2(w[i + 1].v[q])),
                                      H2(w[i + 2].v[q])));
            hpass<false>(V[i].v, m[i].v);
        }

        // image-edge column repair (replicate); commutes with vertical max
        if (edgeL && g16 == 1) {
#pragma unroll
            for (int i = 0; i < 2; ++i) {   // out col12 lo := max(x12,x13)
                u32 d2 = V[i].v[2];
                u32 sw = (d2 >> 16) | (d2 << 16);
                u32 pm = U2(hmax2v(H2(d2), H2(sw)));
                m[i].v[2] = (m[i].v[2] & 0xFFFF0000u) | (pm & 0xFFFFu);
            }
        }
        if (edgeR && g16 == 9) {
#pragma unroll
            for (int i = 0; i < 2; ++i) {   // out col75 hi := max(x74,x75)
                u32 d1 = V[i].v[1];
                u32 sw = (d1 >> 16) | (d1 << 16);
                u32 pm = U2(hmax2v(H2(d1), H2(sw)));
                m[i].v[1] = (m[i].v[1] & 0x0000FFFFu) | (pm & 0xFFFF0000u);
            }
        }

        const u32* pc = cur + rs_d * SD + coldw;
#pragma unroll
        for (int i = 0; i < 2; ++i) {
            U4 a; *(uint4*)a.v = *(const uint4*)(pc + i * SD);
#pragma unroll
            for (int qd = 0; qd < 4; ++qd) {
                hv2 D = H2(m[i].v[qd]);               // dilate-out (already 3x3)
                hv2 z; z[0] = (_Float16)0; z[1] = (_Float16)0;
                hv2 d = hmax2v(H2(a.v[qd]) - D, z);   // d in [0,1]
                hv2 c = Cv[i][qd];
                Cv[i][qd] = c - c * d;                // c' = c*(1-d)  (pk_fma)
            }
        }
    }
    __syncthreads();
}

__global__ __launch_bounds__(512, 8)
void skel_tile_kernel(const float* __restrict__ pred,
                      const float* __restrict__ target,
                      float* __restrict__ ws)
{
    __shared__ __align__(16) u32 bufA[RROWS * SD];
    __shared__ __align__(16) u32 bufB[RROWS * SD];

    const int tid = threadIdx.x;
    const int bc  = blockIdx.z & (NBC - 1);
    const int img = blockIdx.z >> 4;
    const int r0  = blockIdx.y * TILE;
    const int c0  = blockIdx.x * TILE;

    const float* src = (img == 0) ? pred : target;
    const size_t base = (size_t)bc * (size_t)(IMG * IMG);

    const bool edgeT = (blockIdx.y == 0);
    const bool edgeB = (blockIdx.y == 15);
    const bool edgeL = (blockIdx.x == 0);
    const bool edgeR = (blockIdx.x == 15);
    const bool edgeI = !(edgeT || edgeB);
    const int rdLo = edgeT ? 12 : 0;
    const int rdHi = edgeB ? 75 : (RROWS - 1);

    // ---- load region rows 0..87, cols 0..95 (halves), replicate-clamped ----
    for (int t = tid; t < 88 * 12; t += 512) {
        int rr = t / 12;
        int g  = t - rr * 12;
        int gr = min(max(r0 + rr - HALO, 0), IMG - 1);
        const float* rowp = src + base + (size_t)gr * IMG;
        float f[8];
        int gc0 = c0 + 8 * g - HALO;
        if (g <= 10 && gc0 >= 0 && gc0 + 8 <= IMG) {
            float4 v0 = *(const float4*)(rowp + gc0);
            float4 v1 = *(const float4*)(rowp + gc0 + 4);
            f[0] = v0.x; f[1] = v0.y; f[2] = v0.z; f[3] = v0.w;
            f[4] = v1.x; f[5] = v1.y; f[6] = v1.z; f[7] = v1.w;
        } else {
#pragma unroll
            for (int i = 0; i < 8; ++i) {
                int rc = min(8 * g + i, 87);                    // region col clamp (pad cols)
                int gc = min(max(c0 + rc - HALO, 0), IMG - 1);  // image col clamp
                f[i] = rowp[gc];
            }
        }
        U4 u;
#pragma unroll
        for (int q = 0; q < 4; ++q) {
            float a = f[2 * q], b = f[2 * q + 1];
            if (img == 0) { a = sigmoidf(a); b = sigmoidf(b); }
            else { a = fminf(fmaxf(a, 0.f), 1.f); b = fminf(fmaxf(b, 0.f), 1.f); }
            hv2 p; p[0] = (_Float16)a; p[1] = (_Float16)b;
            u.v[q] = U2(p);
        }
        *(uint4*)&bufA[rr * SD + 4 * g] = *(const uint4*)u.v;
    }

    // ---- strip / lane geometry: 32 strips of 16 lanes ----
    const int strip = tid >> 4;                 // 0..31
    const int g16   = tid & 15;                 // lane within DPP row
    const int coldw = 4 * min(g16, 11);         // clamped dword col (16B aligned)
    const bool wact = (g16 < 12);

    // erode bank-phase perm (stride 3*SD==28 mod 32; in-wave Dblk=4 ->
    // Dphase=16): bijective on 0..31.
    const int blk = ((strip & 3) << 2) | (((strip >> 2) & 1) << 4) | (strip >> 3);
    const int rs_d = 12 + 2 * strip;            // dilate out rows rs_d..rs_d+1 (12..75 exact)

    hv2 Cv[2][4];                               // complement: c = 1 - skel
#pragma unroll
    for (int j = 0; j < 2; ++j)
#pragma unroll
        for (int q = 0; q < 4; ++q) { Cv[j][q][0] = (_Float16)1; Cv[j][q][1] = (_Float16)1; }

    u32* cur = bufA;
    u32* oth = bufB;

    __syncthreads();

#pragma unroll 1
    for (int k = 0; k < NITER; ++k) {
        iter_body(k, cur, oth, g16, coldw, wact, blk, rs_d,
                  edgeI, rdLo, rdHi, edgeL, edgeR, Cv);
        u32* t_ = cur; cur = oth; oth = t_;
    }

    // ---- tile sums: sum(skel), sum(skel * other), skel = 1 - c ----
    const float* osrc = (img == 0) ? target : pred;
    float s_sum = 0.0f, sp_sum = 0.0f;
#pragma unroll
    for (int j = 0; j < 2; ++j) {
        int orow = r0 + 2 * strip + j;
#pragma unroll
        for (int q = 0; q < 4; ++q) {
#pragma unroll
            for (int e = 0; e < 2; ++e) {
                int rc = 8 * g16 + 2 * q + e;
                if (rc >= 12 && rc <= 75) {
                    float sv = 1.0f - (float)Cv[j][q][e];
                    float ov = osrc[base + (size_t)orow * IMG + (c0 + rc - HALO)];
                    if (img == 1) ov = sigmoidf(ov);
                    s_sum  += sv;
                    sp_sum += sv * ov;
                }
            }
        }
    }

#pragma unroll
    for (int off = 32; off > 0; off >>= 1) {
        s_sum  += __shfl_down(s_sum,  off, 64);
        sp_sum += __shfl_down(sp_sum, off, 64);
    }
    float* red = (float*)bufA;
    if ((tid & 63) == 0) {
        red[(tid >> 6) * 2 + 0] = sp_sum;
        red[(tid >> 6) * 2 + 1] = s_sum;
    }
    __syncthreads();
    if (tid == 0) {
        float a = ((red[0] + red[2]) + (red[4] + red[6]))
                + ((red[8] + red[10]) + (red[12] + red[14]));
        float b = ((red[1] + red[3]) + (red[5] + red[7]))
                + ((red[9] + red[11]) + (red[13] + red[15]));
        float* acc = ws + (size_t)blockIdx.z * 2;
        atomicAdd(acc + 0, a);   // sum skel * other
        atomicAdd(acc + 1, b);   // sum skel
    }
}

__global__ void finalize_kernel(const float* __restrict__ ws, float* __restrict__ out)
{
    if (threadIdx.x == 0) {
        float acc = 0.0f;
        for (int bc = 0; bc < NBC; ++bc) {
            float spt = ws[(0 * NBC + bc) * 2 + 0];
            float sp  = ws[(0 * NBC + bc) * 2 + 1];
            float stp = ws[(1 * NBC + bc) * 2 + 0];
            float st  = ws[(1 * NBC + bc) * 2 + 1];
            float tprec = spt / (sp + LEPS);
            float tsens = stp / (st + LEPS);
            acc += 1.0f - 2.0f * tprec * tsens / (tprec + tsens + LEPS);
        }
        out[0] = acc / (float)NBC;
    }
}

extern "C" void kernel_launch(void* const* d_in, const int* in_sizes, int n_in,
                              void* d_out, int out_size, void* d_ws, size_t ws_size,
                              hipStream_t stream) {
    const float* pred   = (const float*)d_in[0];
    const float* target = (const float*)d_in[1];
    float* ws  = (float*)d_ws;
    float* out = (float*)d_out;

    hipMemsetAsync(d_ws, 0, 2 * NBC * 2 * sizeof(float), stream);

    dim3 grid(IMG / TILE, IMG / TILE, 2 * NBC);   // 16 x 16 x 32
    skel_tile_kernel<<<grid, 512, 0, stream>>>(pred, target, ws);
    finalize_kernel<<<1, 64, 0, stream>>>(ws, out);
}

// Round 7
// 482.575 us; speedup vs baseline: 1.0131x; 1.0131x over previous
//
#include <hip/hip_runtime.h>

// SoftCLDiceLoss fully fused, round 9: codegen room + erode strip shrink.
// Evidence R6: occupancy 2x -> 0 gain; conflicts 5.6-9.0e7 at const time
// (fully hidden); VALUBusy*dur tracks instruction count -> VALU-work bound,
// and VGPR=24 << ~60 live values means launch_bounds(512,8)'s 64-cap forced
// the allocator into LDS re-reads/serialization (conflicts +60% vs +20%
// modeled). Fix 1: __launch_bounds__(512,6) -> VGPR cap 85, 24 waves/CU.
// Fix 2: erode uses only nact=ceil((86-2k)/3) strips (30..22 of 32, -20%
// erode work); bank-phase perm deleted (non-binding). Complement skel
// update; vertical-first separable morphology; band [min(k+1,11),
// max(86-k,76)]; 2 syncs/iter; 4 blocks/CU (36.6 KB LDS).

#define TILE 64
#define HALO 12
#define RROWS 88
#define SD 52                    // row stride in dwords
#define IMG 1024
#define NBC 16
#define NITER 11
#define LEPS 1e-6f

typedef unsigned int u32;
typedef _Float16 hv2 __attribute__((ext_vector_type(2)));

struct __align__(16) U4 { u32 v[4]; };

__device__ __forceinline__ hv2 H2(u32 x) { union { u32 u; hv2 h; } c; c.u = x; return c.h; }
__device__ __forceinline__ u32 U2(hv2 x) { union { u32 u; hv2 h; } c; c.h = x; return c.u; }
__device__ __forceinline__ hv2 hmin2v(hv2 a, hv2 b) { return __builtin_elementwise_min(a, b); }
__device__ __forceinline__ hv2 hmax2v(hv2 a, hv2 b) { return __builtin_elementwise_max(a, b); }
__device__ __forceinline__ u32 dpp_prev16(u32 x) {   // lane i <- i-1 within 16-lane row, 0-fill
    return (u32)__builtin_amdgcn_update_dpp(0, (int)x, 0x101, 0xf, 0xf, true);
}
__device__ __forceinline__ u32 dpp_next16(u32 x) {   // lane i <- i+1 within 16-lane row, 0-fill
    return (u32)__builtin_amdgcn_update_dpp(0, (int)x, 0x111, 0xf, 0xf, true);
}
__device__ __forceinline__ u32 alignh(u32 hi, u32 lo) {   // (lo.hi16, hi.lo16) packed
    return (u32)((((unsigned long long)hi << 32) | lo) >> 16);
}
__device__ __forceinline__ float sigmoidf(float x) { return 1.0f / (1.0f + __expf(-x)); }

// 3-wide horizontal min/max over 8 packed halves; neighbors via DPP.
template<bool IS_MIN>
__device__ __forceinline__ void hpass(const u32 d[4], u32 o[4]) {
    u32 dm = dpp_prev16(d[3]);
    u32 dp = dpp_next16(d[0]);
    u32 a[5];
    a[0] = alignh(d[0], dm);
    a[1] = alignh(d[1], d[0]);
    a[2] = alignh(d[2], d[1]);
    a[3] = alignh(d[3], d[2]);
    a[4] = alignh(dp,   d[3]);
#pragma unroll
    for (int q = 0; q < 4; ++q) {
        if (IS_MIN) o[q] = U2(hmin2v(hmin2v(H2(a[q]), H2(d[q])), H2(a[q + 1])));
        else        o[q] = U2(hmax2v(hmax2v(H2(a[q]), H2(d[q])), H2(a[q + 1])));
    }
}

// One skel iteration: erode cur->oth (rows [lo,hi], 3 rows/strip, only
// nact=ceil(band/3) strips active), then dilate(oth)+delta(cur)+complement
// update (2 rows/strip). Vertical reduce before hpass in both phases.
__device__ __forceinline__ void iter_body(int k, u32* cur, u32* oth,
        int strip, int g16, int coldw, bool wact, int rs_d,
        bool edgeI, int rdLo, int rdHi, bool edgeL, bool edgeR,
        hv2 (&Cv)[2][4])
{
    // ---- erode 3x3 (min): cur -> oth, vertical-first, 3 rows/strip ----
    const int lo = min(k + 1, 11);           // needed band of erode output
    const int hi = max(86 - k, 76);
    const int nact = (hi - lo + 3) / 3;      // ceil(band/3) active strips
    if (strip < nact) {
        const int rs_e = min(lo + 3 * strip, hi - 2);
        const u32* p = cur + (rs_e - 1) * SD + coldw;
        u32* qo = oth + rs_e * SD + coldw;
        U4 r0, r1, r2;
        *(uint4*)r0.v = *(const uint4*)(p);
        *(uint4*)r1.v = *(const uint4*)(p + SD);
#pragma unroll
        for (int j = 0; j < 3; ++j) {
            *(uint4*)r2.v = *(const uint4*)(p + (j + 2) * SD);
            U4 vv, o;
#pragma unroll
            for (int q = 0; q < 4; ++q)
                vv.v[q] = U2(hmin2v(hmin2v(H2(r0.v[q]), H2(r1.v[q])), H2(r2.v[q])));
            hpass<true>(vv.v, o.v);
            if (wact) *(uint4*)(qo + j * SD) = *(const uint4*)o.v;
            r0 = r1; r1 = r2;
        }
    }
    __syncthreads();

    // ---- dilate 3x3 (max) on oth, vertical-first + delta vs cur + update ----
    {
        U4 w[4];
        if (edgeI) {
            const u32* p = oth + (rs_d - 1) * SD + coldw;
#pragma unroll
            for (int j = 0; j < 4; ++j)
                *(uint4*)w[j].v = *(const uint4*)(p + j * SD);
        } else {
#pragma unroll
            for (int j = 0; j < 4; ++j) {
                int rr = min(max(rs_d - 1 + j, rdLo), rdHi);
                *(uint4*)w[j].v = *(const uint4*)(oth + rr * SD + coldw);
            }
        }
        U4 V[2], m[2];
#pragma unroll
        for (int i = 0; i < 2; ++i) {
#pragma unroll
            for (int q = 0; q < 4; ++q)
                V[i].v[q] = U2(hmax2v(hmax2v(H2(w[i].v[q]), H2(w[i + 1].v[q])),
                                      H2(w[i + 2].v[q])));
            hpass<false>(V[i].v, m[i].v);
        }

        // image-edge column repair (replicate); commutes with vertical max
        if (edgeL && g16 == 1) {
#pragma unroll
            for (int i = 0; i < 2; ++i) {   // out col12 lo := max(x12,x13)
                u32 d2 = V[i].v[2];
                u32 sw = (d2 >> 16) | (d2 << 16);
                u32 pm = U2(hmax2v(H2(d2), H2(sw)));
                m[i].v[2] = (m[i].v[2] & 0xFFFF0000u) | (pm & 0xFFFFu);
            }
        }
        if (edgeR && g16 == 9) {
#pragma unroll
            for (int i = 0; i < 2; ++i) {   // out col75 hi := max(x74,x75)
                u32 d1 = V[i].v[1];
                u32 sw = (d1 >> 16) | (d1 << 16);
                u32 pm = U2(hmax2v(H2(d1), H2(sw)));
                m[i].v[1] = (m[i].v[1] & 0x0000FFFFu) | (pm & 0xFFFF0000u);
            }
        }

        const u32* pc = cur + rs_d * SD + coldw;
#pragma unroll
        for (int i = 0; i < 2; ++i) {
            U4 a; *(uint4*)a.v = *(const uint4*)(pc + i * SD);
#pragma unroll
            for (int qd = 0; qd < 4; ++qd) {
                hv2 D = H2(m[i].v[qd]);               // dilate-out (already 3x3)
                hv2 z; z[0] = (_Float16)0; z[1] = (_Float16)0;
                hv2 d = hmax2v(H2(a.v[qd]) - D, z);   // d in [0,1]
                hv2 c = Cv[i][qd];
                Cv[i][qd] = c - c * d;                // c' = c*(1-d)  (pk_fma)
            }
        }
    }
    __syncthreads();
}

__global__ __launch_bounds__(512, 6)
void skel_tile_kernel(const float* __restrict__ pred,
                      const float* __restrict__ target,
                      float* __restrict__ ws)
{
    __shared__ __align__(16) u32 bufA[RROWS * SD];
    __shared__ __align__(16) u32 bufB[RROWS * SD];

    const int tid = threadIdx.x;
    const int bc  = blockIdx.z & (NBC - 1);
    const int img = blockIdx.z >> 4;
    const int r0  = blockIdx.y * TILE;
    const int c0  = blockIdx.x * TILE;

    const float* src = (img == 0) ? pred : target;
    const size_t base = (size_t)bc * (size_t)(IMG * IMG);

    const bool edgeT = (blockIdx.y == 0);
    const bool edgeB = (blockIdx.y == 15);
    const bool edgeL = (blockIdx.x == 0);
    const bool edgeR = (blockIdx.x == 15);
    const bool edgeI = !(edgeT || edgeB);
    const int rdLo = edgeT ? 12 : 0;
    const int rdHi = edgeB ? 75 : (RROWS - 1);

    // ---- load region rows 0..87, cols 0..95 (halves), replicate-clamped ----
    for (int t = tid; t < 88 * 12; t += 512) {
        int rr = t / 12;
        int g  = t - rr * 12;
        int gr = min(max(r0 + rr - HALO, 0), IMG - 1);
        const float* rowp = src + base + (size_t)gr * IMG;
        float f[8];
        int gc0 = c0 + 8 * g - HALO;
        if (g <= 10 && gc0 >= 0 && gc0 + 8 <= IMG) {
            float4 v0 = *(const float4*)(rowp + gc0);
            float4 v1 = *(const float4*)(rowp + gc0 + 4);
            f[0] = v0.x; f[1] = v0.y; f[2] = v0.z; f[3] = v0.w;
            f[4] = v1.x; f[5] = v1.y; f[6] = v1.z; f[7] = v1.w;
        } else {
#pragma unroll
            for (int i = 0; i < 8; ++i) {
                int rc = min(8 * g + i, 87);                    // region col clamp (pad cols)
                int gc = min(max(c0 + rc - HALO, 0), IMG - 1);  // image col clamp
                f[i] = rowp[gc];
            }
        }
        U4 u;
#pragma unroll
        for (int q = 0; q < 4; ++q) {
            float a = f[2 * q], b = f[2 * q + 1];
            if (img == 0) { a = sigmoidf(a); b = sigmoidf(b); }
            else { a = fminf(fmaxf(a, 0.f), 1.f); b = fminf(fmaxf(b, 0.f), 1.f); }
            hv2 p; p[0] = (_Float16)a; p[1] = (_Float16)b;
            u.v[q] = U2(p);
        }
        *(uint4*)&bufA[rr * SD + 4 * g] = *(const uint4*)u.v;
    }

    // ---- strip / lane geometry: 32 strips of 16 lanes ----
    const int strip = tid >> 4;                 // 0..31
    const int g16   = tid & 15;                 // lane within DPP row
    const int coldw = 4 * min(g16, 11);         // clamped dword col (16B aligned)
    const bool wact = (g16 < 12);

    const int rs_d = 12 + 2 * strip;            // dilate out rows rs_d..rs_d+1 (12..75 exact)

    hv2 Cv[2][4];                               // complement: c = 1 - skel
#pragma unroll
    for (int j = 0; j < 2; ++j)
#pragma unroll
        for (int q = 0; q < 4; ++q) { Cv[j][q][0] = (_Float16)1; Cv[j][q][1] = (_Float16)1; }

    u32* cur = bufA;
    u32* oth = bufB;

    __syncthreads();

#pragma unroll 1
    for (int k = 0; k < NITER; ++k) {
        iter_body(k, cur, oth, strip, g16, coldw, wact, rs_d,
                  edgeI, rdLo, rdHi, edgeL, edgeR, Cv);
        u32* t_ = cur; cur = oth; oth = t_;
    }

    // ---- tile sums: sum(skel), sum(skel * other), skel = 1 - c ----
    const float* osrc = (img == 0) ? target : pred;
    float s_sum = 0.0f, sp_sum = 0.0f;
#pragma unroll
    for (int j = 0; j < 2; ++j) {
        int orow = r0 + 2 * strip + j;
#pragma unroll
        for (int q = 0; q < 4; ++q) {
#pragma unroll
            for (int e = 0; e < 2; ++e) {
                int rc = 8 * g16 + 2 * q + e;
                if (rc >= 12 && rc <= 75) {
                    float sv = 1.0f - (float)Cv[j][q][e];
                    float ov = osrc[base + (size_t)orow * IMG + (c0 + rc - HALO)];
                    if (img == 1) ov = sigmoidf(ov);
                    s_sum  += sv;
                    sp_sum += sv * ov;
                }
            }
        }
    }

#pragma unroll
    for (int off = 32; off > 0; off >>= 1) {
        s_sum  += __shfl_down(s_sum,  off, 64);
        sp_sum += __shfl_down(sp_sum, off, 64);
    }
    float* red = (float*)bufA;
    if ((tid & 63) == 0) {
        red[(tid >> 6) * 2 + 0] = sp_sum;
        red[(tid >> 6) * 2 + 1] = s_sum;
    }
    __syncthreads();
    if (tid == 0) {
        float a = ((red[0] + red[2]) + (red[4] + red[6]))
                + ((red[8] + red[10]) + (red[12] + red[14]));
        float b = ((red[1] + red[3]) + (red[5] + red[7]))
                + ((red[9] + red[11]) + (red[13] + red[15]));
        float* acc = ws + (size_t)blockIdx.z * 2;
        atomicAdd(acc + 0, a);   // sum skel * other
        atomicAdd(acc + 1, b);   // sum skel
    }
}

__global__ void finalize_kernel(const float* __restrict__ ws, float* __restrict__ out)
{
    if (threadIdx.x == 0) {
        float acc = 0.0f;
        for (int bc = 0; bc < NBC; ++bc) {
            float spt = ws[(0 * NBC + bc) * 2 + 0];
            float sp  = ws[(0 * NBC + bc) * 2 + 1];
            float stp = ws[(1 * NBC + bc) * 2 + 0];
            float st  = ws[(1 * NBC + bc) * 2 + 1];
            float tprec = spt / (sp + LEPS);
            float tsens = stp / (st + LEPS);
            acc += 1.0f - 2.0f * tprec * tsens / (tprec + tsens + LEPS);
        }
        out[0] = acc / (float)NBC;
    }
}

extern "C" void kernel_launch(void* const* d_in, const int* in_sizes, int n_in,
                              void* d_out, int out_size, void* d_ws, size_t ws_size,
                              hipStream_t stream) {
    const float* pred   = (const float*)d_in[0];
    const float* target = (const float*)d_in[1];
    float* ws  = (float*)d_ws;
    float* out = (float*)d_out;

    hipMemsetAsync(d_ws, 0, 2 * NBC * 2 * sizeof(float), stream);

    dim3 grid(IMG / TILE, IMG / TILE, 2 * NBC);   // 16 x 16 x 32
    skel_tile_kernel<<<grid, 512, 0, stream>>>(pred, target, ws);
    finalize_kernel<<<1, 64, 0, stream>>>(ws, out);
}